// Round 6
// baseline (156.899 us; speedup 1.0000x reference)
//
#include <hip/hip_runtime.h>
#include <stdint.h>

typedef float f32x4 __attribute__((ext_vector_type(4)));
typedef _Float16 f16;
typedef f16 f16x8 __attribute__((ext_vector_type(8)));
typedef f16 f16x4 __attribute__((ext_vector_type(4)));

#define MFMA16(a, b, c) __builtin_amdgcn_mfma_f32_16x16x32_f16((a), (b), (c), 0, 0, 0)

#define SBAR() do { __builtin_amdgcn_sched_barrier(0); \
                    __builtin_amdgcn_s_barrier();      \
                    __builtin_amdgcn_sched_barrier(0); } while (0)

typedef __attribute__((address_space(1))) const uint32_t gu32;
typedef __attribute__((address_space(3))) uint32_t lu32;
__device__ __forceinline__ void gload_lds16(const void* g, void* l) {
    __builtin_amdgcn_global_load_lds((gu32*)g, (lu32*)l, 16, 0, 0);
}

// K/V tile image: per (head bh, kv-tile kt) a contiguous 4096-elem (8 KB)
// buffer; elem (row, k) at  row*64 + (((k>>3) ^ (row&7)) << 3) + (k&7).
__device__ __forceinline__ size_t kv_elem(int bh, int n, int d) {
    const int kt = n >> 6, row = n & 63;
    return ((size_t)(bh * 32 + kt)) * 4096 + row * 64 + (((d >> 3) ^ (row & 7)) << 3) + (d & 7);
}

// ---------------------------------------------------------------------------
// Kernel 1: convert fp32 inputs to fp16 (X split hi/lo; w_qkv rows permuted).
// ---------------------------------------------------------------------------
__global__ void split_inputs(const float* __restrict__ X, const float* __restrict__ Wq,
                             const float* __restrict__ Wf,
                             f16* __restrict__ Xh, f16* __restrict__ Xl,
                             f16* __restrict__ Wh, f16* __restrict__ Wfb) {
    const int tid = blockIdx.x * 256 + threadIdx.x;
    if (tid < 393216) {                       // X: 3,145,728 floats
        const float* s = X + (size_t)tid * 8;
        f16 hi[8], lo[8];
#pragma unroll
        for (int j = 0; j < 8; j += 4) {
            f32x4 v = *(const f32x4*)(s + j);
#pragma unroll
            for (int q = 0; q < 4; ++q) {
                f16 h = (f16)v[q];
                hi[j + q] = h;
                lo[j + q] = (f16)(v[q] - (float)h);
            }
        }
        *(f16x8*)(Xh + (size_t)tid * 8) = *(f16x8*)hi;
        *(f16x8*)(Xl + (size_t)tid * 8) = *(f16x8*)lo;
    } else if (tid < 614400) {                // w_qkv: row c*768+d*12+h -> c*768+h*64+d
        const int t2 = tid - 393216;
        const int row = t2 / 96;
        const int k = (t2 % 96) * 8;
        const int c = row / 768;
        const int rem = row - c * 768;
        const int d = rem / 12;
        const int h2 = rem - d * 12;
        const int cp = c * 768 + h2 * 64 + d;
        const float* s = Wq + (size_t)row * 768 + k;
        f16 hi[8];
#pragma unroll
        for (int j = 0; j < 8; j += 4) {
            f32x4 v = *(const f32x4*)(s + j);
#pragma unroll
            for (int q = 0; q < 4; ++q) hi[j + q] = (f16)v[q];
        }
        *(f16x8*)(Wh + (size_t)cp * 768 + k) = *(f16x8*)hi;
    } else {                                  // w_fc
        const int t2 = tid - 614400;
        const float* s = Wf + (size_t)t2 * 8;
        f16 hi[8];
#pragma unroll
        for (int j = 0; j < 8; j += 4) {
            f32x4 v = *(const f32x4*)(s + j);
#pragma unroll
            for (int q = 0; q < 4; ++q) hi[j + q] = (f16)v[q];
        }
        *(f16x8*)(Wfb + (size_t)t2 * 8) = *(f16x8*)hi;
    }
}

// ---------------------------------------------------------------------------
// Kernel 2: qkv GEMM, fp16, 2-phase double-buffered staging (counted vmcnt,
// raw barriers). Q cols x(hi+lo) = 2 MFMA; K/V handled same split for K,
// single for V. Epilogue: Q scaled by 8*log2e, split hi/lo; K -> swizzled
// image; V linear. grid (32, 18), block 256.
// ---------------------------------------------------------------------------
__global__ __launch_bounds__(256) void qkv_gemm(
    const f16* __restrict__ Xh, const f16* __restrict__ Xl,
    const f16* __restrict__ Wh,
    f16* __restrict__ Qh, f16* __restrict__ Ql,
    f16* __restrict__ Khg, f16* __restrict__ Vb) {
    __shared__ f16 Ah[2][4096], Al[2][4096], Bh[2][4096];
    const int t = threadIdx.x;
    const int lane = t & 63, wv = t >> 6;
    const int wm = (wv >> 1) * 64, wn = (wv & 1) * 64;
    const int r = lane & 15, g = lane >> 4;
    const int bm = blockIdx.x, bn = blockIdx.y;
    const bool full = (bn < 12);   // Q/K get the x-lo pass; V doesn't

    const int lrow = lane >> 2;
    const int lk = (lane & 3) * 8;

    f32x4 acc[4][4];
#pragma unroll
    for (int i = 0; i < 4; ++i)
#pragma unroll
        for (int j = 0; j < 4; ++j) acc[i][j] = (f32x4)0.0f;

    auto stage = [&](int ksi, int buf) {
#pragma unroll
        for (int hh = 0; hh < 2; ++hh) {
            const int ii = wv * 2 + hh;
            const int grow = ii * 16 + lrow;
            const size_t ga = (size_t)(bm * 128 + grow) * 768 + ksi * 32 + lk;
            const size_t gb = (size_t)(bn * 128 + grow) * 768 + ksi * 32 + lk;
            gload_lds16(Xh + ga, &Ah[buf][ii * 512]);
            gload_lds16(Wh + gb, &Bh[buf][ii * 512]);
            if (full) gload_lds16(Xl + ga, &Al[buf][ii * 512]);
        }
    };

    stage(0, 0);
    int cur = 0;
    for (int i = 0; i < 24; ++i) {
        if (i < 23) {
            stage(i + 1, cur ^ 1);
            if (full) asm volatile("s_waitcnt vmcnt(6)" ::: "memory");
            else      asm volatile("s_waitcnt vmcnt(4)" ::: "memory");
        } else {
            asm volatile("s_waitcnt vmcnt(0)" ::: "memory");
        }
        SBAR();

        f16x8 a_h[4], b[4];
#pragma unroll
        for (int mf = 0; mf < 4; ++mf) a_h[mf] = *(f16x8*)&Ah[cur][(wm + mf * 16 + r) * 32 + g * 8];
#pragma unroll
        for (int nf = 0; nf < 4; ++nf) b[nf] = *(f16x8*)&Bh[cur][(wn + nf * 16 + r) * 32 + g * 8];
        if (full) {
            f16x8 a_l[4];
#pragma unroll
            for (int mf = 0; mf < 4; ++mf) a_l[mf] = *(f16x8*)&Al[cur][(wm + mf * 16 + r) * 32 + g * 8];
#pragma unroll
            for (int mf = 0; mf < 4; ++mf)
#pragma unroll
                for (int nf = 0; nf < 4; ++nf) {
                    acc[mf][nf] = MFMA16(a_h[mf], b[nf], acc[mf][nf]);
                    acc[mf][nf] = MFMA16(a_l[mf], b[nf], acc[mf][nf]);
                }
        } else {
#pragma unroll
            for (int mf = 0; mf < 4; ++mf)
#pragma unroll
                for (int nf = 0; nf < 4; ++nf)
                    acc[mf][nf] = MFMA16(a_h[mf], b[nf], acc[mf][nf]);
        }
        SBAR();
        cur ^= 1;
    }

    const int comp = bn / 6;
#pragma unroll
    for (int mf = 0; mf < 4; ++mf)
#pragma unroll
        for (int nf = 0; nf < 4; ++nf) {
            const int col = bn * 128 + wn + nf * 16 + r;
            const int h = (col >> 6) % 12;
            const int d = col & 63;
#pragma unroll
            for (int v = 0; v < 4; ++v) {
                const int row = bm * 128 + wm + mf * 16 + g * 4 + v;
                const int b2 = row >> 11, n = row & 2047;
                const int bh = b2 * 12 + h;
                float val = acc[mf][nf][v];
                if (comp == 0) {
                    const size_t dest = ((size_t)bh * 2048 + n) * 64 + d;
                    val *= 11.5415603372917f;  // 8 * log2(e): temperature + exp2-space
                    f16 hi = (f16)val;
                    Qh[dest] = hi;
                    Ql[dest] = (f16)(val - (float)hi);
                } else if (comp == 1) {
                    Khg[kv_elem(bh, n, d)] = (f16)val;
                } else {
                    Vb[((size_t)bh * 2048 + n) * 64 + d] = (f16)val;
                }
            }
        }
}

// ---------------------------------------------------------------------------
// Kernel 2b: V transpose into the tiled+swizzled image. grid 768, block 256.
// ---------------------------------------------------------------------------
__global__ void v_transpose(const f16* __restrict__ Vb, f16* __restrict__ VTg) {
    __shared__ f16 Vt[64 * 72];
    const int t = threadIdx.x;
    const int tile = blockIdx.x;              // bh*32 + kt
    const f16* src = Vb + (size_t)tile * 4096;
    const int row = t >> 2, d0 = (t & 3) * 16;
    *(f16x8*)&Vt[row * 72 + d0]     = *(const f16x8*)(src + row * 64 + d0);
    *(f16x8*)&Vt[row * 72 + d0 + 8] = *(const f16x8*)(src + row * 64 + d0 + 8);
    __syncthreads();
    f16* dst = VTg + (size_t)tile * 4096;
#pragma unroll
    for (int it = 0; it < 2; ++it) {
        const int c = t + it * 256;           // chunk: d = c>>3, sg = c&7
        const int d = c >> 3, sg = c & 7;
        const int kv0 = (sg ^ (d & 7)) * 8;
        f16 o[8];
#pragma unroll
        for (int j = 0; j < 8; ++j) o[j] = Vt[(kv0 + j) * 72 + d];
        *(f16x8*)(dst + (size_t)c * 8) = *(f16x8*)o;
    }
}

// ---------------------------------------------------------------------------
// Kernel 3: flash attention, swapped QK^T, exp2-space softmax with defer-max,
// 2-phase double-buffered K/V staging (counted vmcnt + raw barriers).
// 64 Q rows/block (4 waves x 16). grid 768, block 256. LDS 41 KB.
// ---------------------------------------------------------------------------
__global__ __launch_bounds__(256) void attn_kernel(
    const f16* __restrict__ Qh, const f16* __restrict__ Ql,
    const f16* __restrict__ Khg, const f16* __restrict__ VTg,
    f16* __restrict__ AO) {
    __shared__ f16 Khs[2][4096], VTs[2][4096];
    __shared__ f16 Pl[4][16 * 72];

    const int t = threadIdx.x;
    const int lane = t & 63, wv = t >> 6;
    const int r = lane & 15, g = lane >> 4;
    const int bh = blockIdx.x >> 5;   // 0..23
    const int qb = blockIdx.x & 31;
    const size_t headoff = (size_t)bh * 2048 * 64;
    const int q0 = qb * 64 + wv * 16;

    // Q fragments (B-operand): lane (r,g) holds Q[q0+r][kc*32+g*8 .. +7]
    f16x8 qh[2], ql[2];
#pragma unroll
    for (int kc = 0; kc < 2; ++kc) {
        const size_t off = headoff + (size_t)(q0 + r) * 64 + kc * 32 + g * 8;
        qh[kc] = *(const f16x8*)(Qh + off);
        ql[kc] = *(const f16x8*)(Ql + off);
    }

    f32x4 o_acc[4];
    float m_run = -1e30f, l_run = 0.0f;   // stats for row q0 + r (per lane)
#pragma unroll
    for (int df = 0; df < 4; ++df) o_acc[df] = (f32x4)0.0f;

    auto stage = [&](int kt, int buf) {
        const size_t tb = ((size_t)bh * 32 + kt) * 4096;
#pragma unroll
        for (int c2 = 0; c2 < 2; ++c2) {
            const int c = wv * 2 + c2;
            const int go = c * 512 + lane * 8;
            gload_lds16(Khg + tb + go, &Khs[buf][c * 512]);
            gload_lds16(VTg + tb + go, &VTs[buf][c * 512]);
        }
    };

    stage(0, 0);
    int cur = 0;
    for (int kt = 0; kt < 32; ++kt) {
        if (kt < 31) {
            stage(kt + 1, cur ^ 1);
            asm volatile("s_waitcnt vmcnt(4)" ::: "memory");
        } else {
            asm volatile("s_waitcnt vmcnt(0)" ::: "memory");
        }
        SBAR();

        // ---- S^T = K Q^T : lane (r,g) gets S[q=r][k=cf*16+g*4+v] (log2 units)
        f32x4 s[4];
#pragma unroll
        for (int cf = 0; cf < 4; ++cf) s[cf] = (f32x4)0.0f;
#pragma unroll
        for (int kc = 0; kc < 2; ++kc) {
            const int swz = (((kc * 4 + g) ^ (r & 7)) << 3);
            f16x8 ka[4];
#pragma unroll
            for (int cf = 0; cf < 4; ++cf) ka[cf] = *(f16x8*)&Khs[cur][(cf * 16 + r) * 64 + swz];
#pragma unroll
            for (int cf = 0; cf < 4; ++cf) {
                s[cf] = MFMA16(ka[cf], qh[kc], s[cf]);
                s[cf] = MFMA16(ka[cf], ql[kc], s[cf]);
            }
        }

        // ---- online softmax in exp2-space, defer-max THR=8 (P <= 2^8)
        float mx = -1e30f;
#pragma unroll
        for (int cf = 0; cf < 4; ++cf)
#pragma unroll
            for (int v = 0; v < 4; ++v) mx = fmaxf(mx, s[cf][v]);
        mx = fmaxf(mx, __shfl_xor(mx, 16));
        mx = fmaxf(mx, __shfl_xor(mx, 32));
        if (__any(mx - m_run > 8.0f)) {
            const float mn = fmaxf(m_run, mx);
            const float sc = exp2f(m_run - mn);
            m_run = mn;
            l_run *= sc;
#pragma unroll
            for (int v = 0; v < 4; ++v) {
                const float scv = __shfl(sc, g * 4 + v);
#pragma unroll
                for (int df = 0; df < 4; ++df) o_acc[df][v] *= scv;
            }
        }
        float rs = 0.0f;
        f16 p16[4][4];
#pragma unroll
        for (int cf = 0; cf < 4; ++cf)
#pragma unroll
            for (int v = 0; v < 4; ++v) {
                const float p = exp2f(s[cf][v] - m_run);
                rs += p;
                p16[cf][v] = (f16)p;
            }
        rs += __shfl_xor(rs, 16);
        rs += __shfl_xor(rs, 32);
        l_run += rs;

        // ---- write P (row q=r, cols cf*16+g*4 .. +3), wave-private LDS
#pragma unroll
        for (int cf = 0; cf < 4; ++cf)
            *(f16x4*)&Pl[wv][r * 72 + cf * 16 + g * 4] = *(f16x4*)p16[cf];

        asm volatile("s_waitcnt lgkmcnt(0)" ::: "memory");
        __builtin_amdgcn_sched_barrier(0);

        // ---- O += P @ V
#pragma unroll
        for (int kc = 0; kc < 2; ++kc) {
            f16x8 pa = *(f16x8*)&Pl[wv][r * 72 + kc * 32 + g * 8];
            const int swz = (((kc * 4 + g) ^ (r & 7)) << 3);
#pragma unroll
            for (int df = 0; df < 4; ++df) {
                f16x8 vb = *(f16x8*)&VTs[cur][(df * 16 + r) * 64 + swz];
                o_acc[df] = MFMA16(pa, vb, o_acc[df]);
            }
        }
        SBAR();
        cur ^= 1;
    }

    // ---- finalize: rows of o_acc are g*4+v; l for that row sits at lane g*4+v
    const int bb = bh / 12, hh = bh % 12;
#pragma unroll
    for (int v = 0; v < 4; ++v) {
        const float lv = __shfl(l_run, g * 4 + v);
        const float inv = 1.0f / lv;
        const int n = q0 + g * 4 + v;
#pragma unroll
        for (int df = 0; df < 4; ++df) {
            const int col = hh * 64 + df * 16 + r;
            AO[(size_t)(bb * 2048 + n) * 768 + col] = (f16)(o_acc[df][v] * inv);
        }
    }
}

// ---------------------------------------------------------------------------
// Kernel 4: out = AO @ Wfb^T + b_fc  (fp16 in, fp32 out). grid (32,6).
// ---------------------------------------------------------------------------
__global__ __launch_bounds__(256) void fc_gemm(const f16* __restrict__ A,
                                               const f16* __restrict__ Wfb,
                                               const float* __restrict__ bias,
                                               float* __restrict__ OUT) {
    __shared__ f16 As[128 * 72], Bs[128 * 72];
    const int t = threadIdx.x;
    const int lane = t & 63, wv = t >> 6;
    const int wm = (wv >> 1) * 64, wn = (wv & 1) * 64;
    const int r = lane & 15, g = lane >> 4;
    const int bm = blockIdx.x, bn = blockIdx.y;

    f32x4 acc[4][4];
#pragma unroll
    for (int i = 0; i < 4; ++i)
#pragma unroll
        for (int j = 0; j < 4; ++j) acc[i][j] = (f32x4)0.0f;

    for (int ks = 0; ks < 768; ks += 64) {
#pragma unroll
        for (int it = 0; it < 4; ++it) {
            const int row = (t >> 3) + it * 32;
            const int d0 = (t & 7) * 8;
            *(f16x8*)&As[row * 72 + d0] =
                *(const f16x8*)(A + (size_t)(bm * 128 + row) * 768 + ks + d0);
        }
#pragma unroll
        for (int it = 0; it < 2; ++it) {
            const int row = (t >> 2) + it * 64;
            const int k0 = (t & 3) * 16;
            const f16* wx = Wfb + (size_t)(bn * 128 + row) * 768 + ks + k0;
            *(f16x8*)&Bs[row * 72 + k0]     = *(const f16x8*)wx;
            *(f16x8*)&Bs[row * 72 + k0 + 8] = *(const f16x8*)(wx + 8);
        }
        __syncthreads();

#pragma unroll
        for (int kc = 0; kc < 2; ++kc) {
            const int koff = kc * 32 + g * 8;
            f16x8 a[4], b[4];
#pragma unroll
            for (int mf = 0; mf < 4; ++mf) a[mf] = *(f16x8*)&As[(wm + mf * 16 + r) * 72 + koff];
#pragma unroll
            for (int nf = 0; nf < 4; ++nf) b[nf] = *(f16x8*)&Bs[(wn + nf * 16 + r) * 72 + koff];
#pragma unroll
            for (int mf = 0; mf < 4; ++mf)
#pragma unroll
                for (int nf = 0; nf < 4; ++nf)
                    acc[mf][nf] = MFMA16(a[mf], b[nf], acc[mf][nf]);
        }
        __syncthreads();
    }

#pragma unroll
    for (int nf = 0; nf < 4; ++nf) {
        const int col = bn * 128 + wn + nf * 16 + r;
        const float bv = bias[col];
#pragma unroll
        for (int mf = 0; mf < 4; ++mf) {
            const int row = bm * 128 + wm + mf * 16 + g * 4;
#pragma unroll
            for (int v = 0; v < 4; ++v)
                OUT[(size_t)(row + v) * 768 + col] = acc[mf][nf][v] + bv;
        }
    }
}

// ---------------------------------------------------------------------------
extern "C" void kernel_launch(void* const* d_in, const int* in_sizes, int n_in,
                              void* d_out, int out_size, void* d_ws, size_t ws_size,
                              hipStream_t stream) {
    (void)in_sizes; (void)n_in; (void)out_size; (void)ws_size;
    const float* x     = (const float*)d_in[0];   // [2,2048,768]
    const float* w_qkv = (const float*)d_in[1];   // [2304,768]
    const float* w_fc  = (const float*)d_in[2];   // [768,768]
    const float* b_fc  = (const float*)d_in[3];   // [768]
    float* out = (float*)d_out;                   // [2,2048,768] fp32

    char* ws = (char*)d_ws;
    f16* Xh  = (f16*)ws;                         // 3,145,728 elems each (6 MB):
    f16* Xl  = Xh + 3145728;
    f16* Qh  = Xl + 3145728;
    f16* Ql  = Qh + 3145728;
    f16* Khg = Ql + 3145728;
    f16* Vb  = Khg + 3145728;
    f16* VTg = Vb + 3145728;
    f16* AO  = VTg + 3145728;
    f16* Wh  = AO + 3145728;                     // 1,769,472 elems
    f16* Wfb = Wh + 1769472;                     // 589,824 elems
    // total = 55,050,240 B

    split_inputs<<<2688, 256, 0, stream>>>(x, w_qkv, w_fc, Xh, Xl, Wh, Wfb);
    qkv_gemm<<<dim3(32, 18), 256, 0, stream>>>(Xh, Xl, Wh, Qh, Ql, Khg, Vb);
    v_transpose<<<768, 256, 0, stream>>>(Vb, VTg);
    attn_kernel<<<768, 256, 0, stream>>>(Qh, Ql, Khg, VTg, AO);
    fc_gemm<<<dim3(32, 6), 256, 0, stream>>>(AO, Wfb, b_fc, out);
}

// Round 7
// 141.904 us; speedup vs baseline: 1.1057x; 1.1057x over previous
//
#include <hip/hip_runtime.h>
#include <stdint.h>

typedef float f32x4 __attribute__((ext_vector_type(4)));
typedef _Float16 f16;
typedef f16 f16x8 __attribute__((ext_vector_type(8)));
typedef f16 f16x4 __attribute__((ext_vector_type(4)));

#define MFMA16(a, b, c) __builtin_amdgcn_mfma_f32_16x16x32_f16((a), (b), (c), 0, 0, 0)

typedef __attribute__((address_space(1))) const uint32_t gu32;
typedef __attribute__((address_space(3))) uint32_t lu32;
__device__ __forceinline__ void gload_lds16(const void* g, void* l) {
    __builtin_amdgcn_global_load_lds((gu32*)g, (lu32*)l, 16, 0, 0);
}

// K/V tile image: per (head bh, kv-tile kt) a contiguous 4096-elem (8 KB)
// buffer; elem (row, k) at  row*64 + (((k>>3) ^ (row&7)) << 3) + (k&7).
__device__ __forceinline__ size_t kv_elem(int bh, int n, int d) {
    const int kt = n >> 6, row = n & 63;
    return ((size_t)(bh * 32 + kt)) * 4096 + row * 64 + (((d >> 3) ^ (row & 7)) << 3) + (d & 7);
}

// ---------------------------------------------------------------------------
// Kernel 1: convert fp32 inputs to fp16 (X split hi/lo; w_qkv rows permuted).
// (R5 verbatim)
// ---------------------------------------------------------------------------
__global__ void split_inputs(const float* __restrict__ X, const float* __restrict__ Wq,
                             const float* __restrict__ Wf,
                             f16* __restrict__ Xh, f16* __restrict__ Xl,
                             f16* __restrict__ Wh, f16* __restrict__ Wfb) {
    const int tid = blockIdx.x * 256 + threadIdx.x;
    if (tid < 393216) {                       // X: 3,145,728 floats
        const float* s = X + (size_t)tid * 8;
        f16 hi[8], lo[8];
#pragma unroll
        for (int j = 0; j < 8; j += 4) {
            f32x4 v = *(const f32x4*)(s + j);
#pragma unroll
            for (int q = 0; q < 4; ++q) {
                f16 h = (f16)v[q];
                hi[j + q] = h;
                lo[j + q] = (f16)(v[q] - (float)h);
            }
        }
        *(f16x8*)(Xh + (size_t)tid * 8) = *(f16x8*)hi;
        *(f16x8*)(Xl + (size_t)tid * 8) = *(f16x8*)lo;
    } else if (tid < 614400) {                // w_qkv: row c*768+d*12+h -> c*768+h*64+d
        const int t2 = tid - 393216;
        const int row = t2 / 96;
        const int k = (t2 % 96) * 8;
        const int c = row / 768;
        const int rem = row - c * 768;
        const int d = rem / 12;
        const int h2 = rem - d * 12;
        const int cp = c * 768 + h2 * 64 + d;
        const float* s = Wq + (size_t)row * 768 + k;
        f16 hi[8];
#pragma unroll
        for (int j = 0; j < 8; j += 4) {
            f32x4 v = *(const f32x4*)(s + j);
#pragma unroll
            for (int q = 0; q < 4; ++q) hi[j + q] = (f16)v[q];
        }
        *(f16x8*)(Wh + (size_t)cp * 768 + k) = *(f16x8*)hi;
    } else {                                  // w_fc
        const int t2 = tid - 614400;
        const float* s = Wf + (size_t)t2 * 8;
        f16 hi[8];
#pragma unroll
        for (int j = 0; j < 8; j += 4) {
            f32x4 v = *(const f32x4*)(s + j);
#pragma unroll
            for (int q = 0; q < 4; ++q) hi[j + q] = (f16)v[q];
        }
        *(f16x8*)(Wfb + (size_t)t2 * 8) = *(f16x8*)hi;
    }
}

// ---------------------------------------------------------------------------
// Kernel 2: qkv GEMM (R5 verbatim). fp16, Q/K cols 2 MFMA (x hi+lo), V 1.
// ---------------------------------------------------------------------------
__global__ __launch_bounds__(256) void qkv_gemm(
    const f16* __restrict__ Xh, const f16* __restrict__ Xl,
    const f16* __restrict__ Wh,
    f16* __restrict__ Qh, f16* __restrict__ Ql,
    f16* __restrict__ Khg, f16* __restrict__ Vb) {
    __shared__ f16 Ah[128 * 32], Al[128 * 32], Bh[128 * 32];
    const int t = threadIdx.x;
    const int lane = t & 63, wv = t >> 6;
    const int wm = (wv >> 1) * 64, wn = (wv & 1) * 64;
    const int r = lane & 15, g = lane >> 4;
    const int bm = blockIdx.x, bn = blockIdx.y;
    const bool full = (bn < 12);   // Q/K need the x-lo pass; V doesn't

    const int lrow = lane >> 2;
    const int lk = (lane & 3) * 8;

    f32x4 acc[4][4];
#pragma unroll
    for (int i = 0; i < 4; ++i)
#pragma unroll
        for (int j = 0; j < 4; ++j) acc[i][j] = (f32x4)0.0f;

    for (int ks = 0; ks < 768; ks += 32) {
#pragma unroll
        for (int hh = 0; hh < 2; ++hh) {
            const int ii = wv * 2 + hh;
            const int grow = ii * 16 + lrow;
            const size_t ga = (size_t)(bm * 128 + grow) * 768 + ks + lk;
            const size_t gb = (size_t)(bn * 128 + grow) * 768 + ks + lk;
            const int lbase = ii * 512;                  // wave-uniform LDS base
            gload_lds16(Xh + ga, &Ah[lbase]);
            gload_lds16(Wh + gb, &Bh[lbase]);
            if (full) gload_lds16(Xl + ga, &Al[lbase]);
        }
        __syncthreads();

        f16x8 a_h[4], b[4];
#pragma unroll
        for (int mf = 0; mf < 4; ++mf) a_h[mf] = *(f16x8*)&Ah[(wm + mf * 16 + r) * 32 + g * 8];
#pragma unroll
        for (int nf = 0; nf < 4; ++nf) b[nf] = *(f16x8*)&Bh[(wn + nf * 16 + r) * 32 + g * 8];
        if (full) {
            f16x8 a_l[4];
#pragma unroll
            for (int mf = 0; mf < 4; ++mf) a_l[mf] = *(f16x8*)&Al[(wm + mf * 16 + r) * 32 + g * 8];
#pragma unroll
            for (int mf = 0; mf < 4; ++mf)
#pragma unroll
                for (int nf = 0; nf < 4; ++nf) {
                    acc[mf][nf] = MFMA16(a_h[mf], b[nf], acc[mf][nf]);
                    acc[mf][nf] = MFMA16(a_l[mf], b[nf], acc[mf][nf]);
                }
        } else {
#pragma unroll
            for (int mf = 0; mf < 4; ++mf)
#pragma unroll
                for (int nf = 0; nf < 4; ++nf)
                    acc[mf][nf] = MFMA16(a_h[mf], b[nf], acc[mf][nf]);
        }
        __syncthreads();
    }

    const int comp = bn / 6;
#pragma unroll
    for (int mf = 0; mf < 4; ++mf)
#pragma unroll
        for (int nf = 0; nf < 4; ++nf) {
            const int col = bn * 128 + wn + nf * 16 + r;
            const int h = (col >> 6) % 12;
            const int d = col & 63;
#pragma unroll
            for (int v = 0; v < 4; ++v) {
                const int row = bm * 128 + wm + mf * 16 + g * 4 + v;
                const int b2 = row >> 11, n = row & 2047;
                const int bh = b2 * 12 + h;
                float val = acc[mf][nf][v];
                if (comp == 0) {
                    const size_t dest = ((size_t)bh * 2048 + n) * 64 + d;
                    val *= 8.0f;  // fold temperature (reference MULTIPLIES by sqrt(d_k))
                    f16 hi = (f16)val;
                    Qh[dest] = hi;
                    Ql[dest] = (f16)(val - (float)hi);
                } else if (comp == 1) {
                    Khg[kv_elem(bh, n, d)] = (f16)val;
                } else {
                    Vb[((size_t)bh * 2048 + n) * 64 + d] = (f16)val;
                }
            }
        }
}

// ---------------------------------------------------------------------------
// Kernel 2b: V transpose into the tiled+swizzled image (R5 verbatim).
// ---------------------------------------------------------------------------
__global__ void v_transpose(const f16* __restrict__ Vb, f16* __restrict__ VTg) {
    __shared__ f16 Vt[64 * 72];
    const int t = threadIdx.x;
    const int tile = blockIdx.x;              // bh*32 + kt
    const f16* src = Vb + (size_t)tile * 4096;
    const int row = t >> 2, d0 = (t & 3) * 16;
    *(f16x8*)&Vt[row * 72 + d0]     = *(const f16x8*)(src + row * 64 + d0);
    *(f16x8*)&Vt[row * 72 + d0 + 8] = *(const f16x8*)(src + row * 64 + d0 + 8);
    __syncthreads();
    f16* dst = VTg + (size_t)tile * 4096;
#pragma unroll
    for (int it = 0; it < 2; ++it) {
        const int c = t + it * 256;           // chunk: d = c>>3, sg = c&7
        const int d = c >> 3, sg = c & 7;
        const int kv0 = (sg ^ (d & 7)) * 8;
        f16 o[8];
#pragma unroll
        for (int j = 0; j < 8; ++j) o[j] = Vt[(kv0 + j) * 72 + d];
        *(f16x8*)(dst + (size_t)c * 8) = *(f16x8*)o;
    }
}

// ---------------------------------------------------------------------------
// Kernel 3: flash attention PARTIAL (KV-split x2). R5 inner loop verbatim;
// each block does 16 of 32 KV tiles -> grid 1536 -> 6 blocks/CU, 24 waves/CU.
// Writes unnormalized O (fp16) + per-row m,l stats.
// bid = bh*64 + qb*2 + half.  LDS 25.6 KB.
// ---------------------------------------------------------------------------
__global__ __launch_bounds__(256, 6) void attn_partial(
    const f16* __restrict__ Qh, const f16* __restrict__ Ql,
    const f16* __restrict__ Khg, const f16* __restrict__ VTg,
    f16* __restrict__ OP, float* __restrict__ Mst, float* __restrict__ Lst) {
    __shared__ f16 Khs[4096], VTs[4096];
    __shared__ f16 Pl[4][16 * 72];

    const int t = threadIdx.x;
    const int lane = t & 63, wv = t >> 6;
    const int r = lane & 15, g = lane >> 4;
    const int bid = blockIdx.x;
    const int half = bid & 1;
    const int qb = (bid >> 1) & 31;
    const int bh = bid >> 6;          // 0..23
    const size_t headoff = (size_t)bh * 2048 * 64;
    const int q0 = qb * 64 + wv * 16;

    // Q fragments (B-operand): lane (r,g) holds Q[q0+r][kc*32+g*8 .. +7]
    f16x8 qh[2], ql[2];
#pragma unroll
    for (int kc = 0; kc < 2; ++kc) {
        const size_t off = headoff + (size_t)(q0 + r) * 64 + kc * 32 + g * 8;
        qh[kc] = *(const f16x8*)(Qh + off);
        ql[kc] = *(const f16x8*)(Ql + off);
    }

    f32x4 o_acc[4];
    float m_run = -1e30f, l_run = 0.0f;   // stats for row q0 + r (per lane)
#pragma unroll
    for (int df = 0; df < 4; ++df) o_acc[df] = (f32x4)0.0f;

    for (int kt = half * 16; kt < half * 16 + 16; ++kt) {
        // ---- stage K and V^T images (8 KB each, 4 gloads/wave)
        const size_t tb = ((size_t)bh * 32 + kt) * 4096;
#pragma unroll
        for (int c2 = 0; c2 < 2; ++c2) {
            const int c = wv * 2 + c2;
            const int go = c * 512 + lane * 8;
            gload_lds16(Khg + tb + go, &Khs[c * 512]);
            gload_lds16(VTg + tb + go, &VTs[c * 512]);
        }
        __syncthreads();

        // ---- S^T = K Q^T : lane (r,g) gets S[q=r][k=cf*16+g*4+v]
        f32x4 s[4];
#pragma unroll
        for (int cf = 0; cf < 4; ++cf) s[cf] = (f32x4)0.0f;
#pragma unroll
        for (int kc = 0; kc < 2; ++kc) {
            const int swz = (((kc * 4 + g) ^ (r & 7)) << 3);
            f16x8 ka[4];
#pragma unroll
            for (int cf = 0; cf < 4; ++cf) ka[cf] = *(f16x8*)&Khs[(cf * 16 + r) * 64 + swz];
#pragma unroll
            for (int cf = 0; cf < 4; ++cf) {
                s[cf] = MFMA16(ka[cf], qh[kc], s[cf]);
                s[cf] = MFMA16(ka[cf], ql[kc], s[cf]);
            }
        }

        // ---- online softmax, row r owned by this lane (16 vals in-reg)
        float mx = -1e30f;
#pragma unroll
        for (int cf = 0; cf < 4; ++cf)
#pragma unroll
            for (int v = 0; v < 4; ++v) mx = fmaxf(mx, s[cf][v]);
        mx = fmaxf(mx, __shfl_xor(mx, 16));
        mx = fmaxf(mx, __shfl_xor(mx, 32));
        const float mn = fmaxf(m_run, mx);
        const float sc = __expf(m_run - mn);
        m_run = mn;
        float rs = 0.0f;
        f16 p16[4][4];
#pragma unroll
        for (int cf = 0; cf < 4; ++cf)
#pragma unroll
            for (int v = 0; v < 4; ++v) {
                const float p = __expf(s[cf][v] - mn);
                rs += p;
                p16[cf][v] = (f16)p;
            }
        rs += __shfl_xor(rs, 16);
        rs += __shfl_xor(rs, 32);
        l_run = l_run * sc + rs;

        // rescale o_acc: its rows are g*4+v -> fetch sc from lane g*4+v
#pragma unroll
        for (int v = 0; v < 4; ++v) {
            const float scv = __shfl(sc, g * 4 + v);
#pragma unroll
            for (int df = 0; df < 4; ++df) o_acc[df][v] *= scv;
        }

        // ---- write P (row q=r, cols cf*16+g*4 .. +3), wave-private LDS
#pragma unroll
        for (int cf = 0; cf < 4; ++cf)
            *(f16x4*)&Pl[wv][r * 72 + cf * 16 + g * 4] = *(f16x4*)p16[cf];

        asm volatile("s_waitcnt lgkmcnt(0)" ::: "memory");
        __builtin_amdgcn_sched_barrier(0);

        // ---- O += P @ V
#pragma unroll
        for (int kc = 0; kc < 2; ++kc) {
            f16x8 pa = *(f16x8*)&Pl[wv][r * 72 + kc * 32 + g * 8];
            const int swz = (((kc * 4 + g) ^ (r & 7)) << 3);
#pragma unroll
            for (int df = 0; df < 4; ++df) {
                f16x8 vb = *(f16x8*)&VTs[(df * 16 + r) * 64 + swz];
                o_acc[df] = MFMA16(pa, vb, o_acc[df]);
            }
        }
        __syncthreads();
    }

    // ---- write partial: unnormalized O (fp16) + m,l (fp32, one row per lane r)
    const int pb = (bh << 1) + half;
    if (g == 0) {
        Mst[pb * 2048 + q0 + r] = m_run;
        Lst[pb * 2048 + q0 + r] = l_run;
    }
#pragma unroll
    for (int df = 0; df < 4; ++df)
#pragma unroll
        for (int v = 0; v < 4; ++v) {
            const int n = q0 + g * 4 + v;
            OP[((size_t)pb * 2048 + n) * 64 + df * 16 + r] = (f16)o_acc[df][v];
        }
}

// ---------------------------------------------------------------------------
// Kernel 3b: combine the two KV-halves -> AO [b, n, h*64+d] fp16.
// 786432 threads (4 d-elems each), grid 3072.
// ---------------------------------------------------------------------------
__global__ void attn_combine(const f16* __restrict__ OP, const float* __restrict__ Mst,
                             const float* __restrict__ Lst, f16* __restrict__ AO) {
    const int tid = blockIdx.x * 256 + threadIdx.x;
    const int d4 = (tid & 15) * 4;
    const int pr = tid >> 4;          // bh*2048 + n
    const int bh = pr >> 11, n = pr & 2047;
    const int i1 = (bh * 2) * 2048 + n, i2 = i1 + 2048;
    const float m1 = Mst[i1], m2 = Mst[i2];
    const float l1 = Lst[i1], l2 = Lst[i2];
    const float m = fmaxf(m1, m2);
    const float w1 = __expf(m1 - m), w2 = __expf(m2 - m);
    const float inv = 1.0f / (w1 * l1 + w2 * l2);
    f16x4 o1 = *(const f16x4*)(OP + (size_t)i1 * 64 + d4);
    f16x4 o2 = *(const f16x4*)(OP + (size_t)i2 * 64 + d4);
    const int b = bh / 12, h = bh - b * 12;
    f16 out[4];
#pragma unroll
    for (int j = 0; j < 4; ++j)
        out[j] = (f16)((w1 * (float)o1[j] + w2 * (float)o2[j]) * inv);
    *(f16x4*)(AO + ((size_t)(b * 2048 + n)) * 768 + h * 64 + d4) = *(f16x4*)out;
}

// ---------------------------------------------------------------------------
// Kernel 4: out = AO @ Wfb^T + b_fc. 64x64 tiles, XOR-swizzled LDS,
// grid (64, 12) = 768 blocks (was 192).
// ---------------------------------------------------------------------------
__global__ __launch_bounds__(256) void fc_gemm(const f16* __restrict__ A,
                                               const f16* __restrict__ Wfb,
                                               const float* __restrict__ bias,
                                               float* __restrict__ OUT) {
    __shared__ f16 As[64 * 64], Bs[64 * 64];
    const int t = threadIdx.x;
    const int lane = t & 63, wv = t >> 6;
    const int wm = (wv >> 1) * 32, wn = (wv & 1) * 32;
    const int r = lane & 15, g = lane >> 4;
    const int bm = blockIdx.x, bn = blockIdx.y;

    f32x4 acc[2][2];
#pragma unroll
    for (int i = 0; i < 2; ++i)
#pragma unroll
        for (int j = 0; j < 2; ++j) acc[i][j] = (f32x4)0.0f;

    const int srow = t >> 2;
    const int ssg = (t & 3) * 2;

    for (int ks = 0; ks < 768; ks += 64) {
        const f16* as = A + (size_t)(bm * 64 + srow) * 768 + ks;
        const f16* bs = Wfb + (size_t)(bn * 64 + srow) * 768 + ks;
#pragma unroll
        for (int u = 0; u < 2; ++u) {
            const int sg = ssg + u;
            const int dst = srow * 64 + ((sg ^ (srow & 7)) << 3);
            *(f16x8*)&As[dst] = *(const f16x8*)(as + sg * 8);
            *(f16x8*)&Bs[dst] = *(const f16x8*)(bs + sg * 8);
        }
        __syncthreads();

#pragma unroll
        for (int kc = 0; kc < 2; ++kc) {
            f16x8 a[2], b[2];
#pragma unroll
            for (int mf = 0; mf < 2; ++mf) {
                const int row = wm + mf * 16 + r;
                a[mf] = *(f16x8*)&As[row * 64 + (((kc * 4 + g) ^ (row & 7)) << 3)];
            }
#pragma unroll
            for (int nf = 0; nf < 2; ++nf) {
                const int row = wn + nf * 16 + r;
                b[nf] = *(f16x8*)&Bs[row * 64 + (((kc * 4 + g) ^ (row & 7)) << 3)];
            }
#pragma unroll
            for (int mf = 0; mf < 2; ++mf)
#pragma unroll
                for (int nf = 0; nf < 2; ++nf)
                    acc[mf][nf] = MFMA16(a[mf], b[nf], acc[mf][nf]);
        }
        __syncthreads();
    }

#pragma unroll
    for (int nf = 0; nf < 2; ++nf) {
        const int col = bn * 64 + wn + nf * 16 + r;
        const float bv = bias[col];
#pragma unroll
        for (int mf = 0; mf < 2; ++mf) {
            const int row = bm * 64 + wm + mf * 16 + g * 4;
#pragma unroll
            for (int v = 0; v < 4; ++v)
                OUT[(size_t)(row + v) * 768 + col] = acc[mf][nf][v] + bv;
        }
    }
}

// ---------------------------------------------------------------------------
extern "C" void kernel_launch(void* const* d_in, const int* in_sizes, int n_in,
                              void* d_out, int out_size, void* d_ws, size_t ws_size,
                              hipStream_t stream) {
    (void)in_sizes; (void)n_in; (void)out_size; (void)ws_size;
    const float* x     = (const float*)d_in[0];   // [2,2048,768]
    const float* w_qkv = (const float*)d_in[1];   // [2304,768]
    const float* w_fc  = (const float*)d_in[2];   // [768,768]
    const float* b_fc  = (const float*)d_in[3];   // [768]
    float* out = (float*)d_out;                   // [2,2048,768] fp32

    char* ws = (char*)d_ws;
    f16* Xh  = (f16*)ws;                         // 3,145,728 elems each (6 MB):
    f16* Xl  = Xh + 3145728;
    f16* Qh  = Xl + 3145728;
    f16* Ql  = Qh + 3145728;
    f16* Khg = Ql + 3145728;
    f16* Vb  = Khg + 3145728;
    f16* VTg = Vb + 3145728;
    f16* AO  = VTg + 3145728;
    f16* Wh  = AO + 3145728;                     // 1,769,472 elems
    f16* Wfb = Wh + 1769472;                     // 589,824 elems
    float* Mst = (float*)(Wfb + 589824);         // 98,304 floats
    float* Lst = Mst + 98304;                    // 98,304 floats
    // OP (48*2048*64 = 6,291,456 f16) aliases [Xh|Xl] — X dead after qkv_gemm.
    f16* OP = Xh;
    // total = 55,836,672 B

    split_inputs<<<2688, 256, 0, stream>>>(x, w_qkv, w_fc, Xh, Xl, Wh, Wfb);
    qkv_gemm<<<dim3(32, 18), 256, 0, stream>>>(Xh, Xl, Wh, Qh, Ql, Khg, Vb);
    v_transpose<<<768, 256, 0, stream>>>(Vb, VTg);
    attn_partial<<<1536, 256, 0, stream>>>(Qh, Ql, Khg, VTg, OP, Mst, Lst);
    attn_combine<<<3072, 256, 0, stream>>>(OP, Mst, Lst, AO);
    fc_gemm<<<dim3(64, 12), 256, 0, stream>>>(AO, Wfb, b_fc, out);
}